// Round 16
// baseline (1405.872 us; speedup 1.0000x reference)
//
#include <hip/hip_runtime.h>
#include <hip/hip_bf16.h>

// LSTM B=256,T=512,I=64,H=256. Round 16: 2-way j-split. 32 WGs = 16 chunks x
// 2 j-halves, 1024 thr. Each wave owns TWO 16-col gate blocks (80 weight
// VGPRs) -> A-fragments reused 2x (halves the r13 LDS-pipe floor per work),
// fan-in drops to 1 partner. Exchange protocol = r8 exactly (cell -> imme-
// diate coalesced u32 atomicExch publish; wide sc0 sc1 self-validating poll).

#define B_TOT 256
#define T_SEQ 512
#define NIN   64
#define HID   256
#define CHUNK 16
#define JSL   128           // j per WG (2-way split)
#define ROWB  768           // LDS act row stride bytes (320 f16 = 640B data)
#define NKK   10            // K = 320 = 10*32
#define NWG   32

typedef _Float16 half8 __attribute__((ext_vector_type(8)));
typedef float    f32x4 __attribute__((ext_vector_type(4)));
typedef unsigned u32x4 __attribute__((ext_vector_type(4)));

__device__ __forceinline__ float fast_rcp(float x){ return __builtin_amdgcn_rcpf(x); }
__device__ __forceinline__ float sigf(float v){ return fast_rcp(1.0f+__expf(-v)); }
__device__ __forceinline__ float tanhf_fast(float v){ return 1.0f-2.0f*fast_rcp(__expf(2.0f*v)+1.0f); }
__device__ __forceinline__ unsigned short f2h_bits(float f){
    _Float16 h=(_Float16)f; return __builtin_bit_cast(unsigned short,h);
}

__global__ void __launch_bounds__(1024, 4)
lstm_scan(const float* __restrict__ x,
          const float* __restrict__ Wih,
          const float* __restrict__ Whh,
          const float* __restrict__ bih,
          const float* __restrict__ bhh,
          const float* __restrict__ Wfc,
          const float* __restrict__ bfc,
          float* __restrict__ out,
          unsigned* __restrict__ hq)    // [2][B_TOT][HID] tagged h words
{
    __shared__ __align__(16) char act[CHUNK*ROWB];   // [16 rows][320 f16] swizzled
    __shared__ float gl[CHUNK][4*JSL + 1];           // [16][513] gate pre-acts

    const int tid  = threadIdx.x;
    const int w    = tid >> 6;       // wave 0..15 (= batch row in cell phase)
    const int lane = tid & 63;
    const int lr   = lane & 15;
    const int kg   = lane >> 4;
    const int chunk= blockIdx.x & 15;
    const int jw   = blockIdx.x >> 4;    // 0..1
    const int cb   = chunk*CHUNK;

    // wave w owns gate-cols {b*256 + w*16 + lr} for b=0,1 within the WG's
    // 512-col space (col = g*128 + j, g in [0,4), j in [0,128))
    int nidx[2];
    #pragma unroll
    for (int b = 0; b < 2; ++b) {
        const int c = b*256 + w*16 + lr;
        nidx[b] = (c >> 7)*HID + jw*JSL + (c & 127);
    }

    // ---- register-resident weight fragments, 2 blocks = 80 VGPRs ----
    half8 wv[2][NKK];
    float bias[2];
    #pragma unroll
    for (int b = 0; b < 2; ++b) {
        const int n = nidx[b];
        bias[b] = bih[n] + bhh[n];
        #pragma unroll
        for (int kk = 0; kk < 2; ++kk)
            #pragma unroll
            for (int jj = 0; jj < 8; ++jj)
                wv[b][kk][jj] = (_Float16)Wih[n*NIN + kk*32 + kg*8 + jj];
        #pragma unroll
        for (int kk = 2; kk < NKK; ++kk)
            #pragma unroll
            for (int jj = 0; jj < 8; ++jj)
                wv[b][kk][jj] = (_Float16)Whh[n*HID + (kk-2)*32 + kg*8 + jj];
    }

    // ---- init act: zeros (h_0 = 0) then x_0 ----
    for (int i = tid; i < CHUNK*ROWB/4; i += 1024) ((int*)act)[i] = 0;
    __syncthreads();
    {
        float x0 = x[((size_t)(cb + w)*T_SEQ + 0)*NIN + lane];
        *(unsigned short*)(act + w*ROWB + ((lane*2) ^ (w << 4))) = f2h_bits(x0);
    }
    __syncthreads();

    float cst0 = 0.f, cst1 = 0.f, hl0 = 0.f, hl1 = 0.f;

    const int pjw = 1 - jw;          // the single partner j-half
    const int gq  = lane & 31;       // poll quad (lanes 0..31 active)
    const bool pact = (lane < 32);

    for (int t = 0; t < T_SEQ; ++t) {
        // prefetch x_{t+1} (consumed before any poll asm)
        const int tn = (t+1 < T_SEQ) ? t+1 : T_SEQ-1;
        const float xv = x[((size_t)(cb + w)*T_SEQ + tn)*NIN + lane];

        // A fragments (row lr, swizzled, conflict-free); reused by BOTH blocks
        f32x4 aca = {bias[0], bias[0], bias[0], bias[0]};
        f32x4 acb = {bias[1], bias[1], bias[1], bias[1]};
        #pragma unroll
        for (int kk = 0; kk < NKK; ++kk) {
            const int off = (kk*64 + kg*16) ^ (lr << 4);
            const half8 af = *(const half8*)(act + lr*ROWB + off);
            aca = __builtin_amdgcn_mfma_f32_16x16x32_f16(af, wv[0][kk], aca, 0, 0, 0);
            acb = __builtin_amdgcn_mfma_f32_16x16x32_f16(af, wv[1][kk], acb, 0, 0, 0);
        }

        // scatter pre-activations: (row kg*4+r, col b*256 + w*16 + lr)
        #pragma unroll
        for (int r = 0; r < 4; ++r) {
            gl[kg*4 + r][      w*16 + lr] = aca[r];
            gl[kg*4 + r][256 + w*16 + lr] = acb[r];
        }
        __syncthreads();   // B1: gl ready; af reads done -> act writable

        // cell update: thread owns (row=w, j = jw*128 + {lane, lane+64})
        const float iv0 = sigf(gl[w][      lane]);
        const float fv0 = sigf(gl[w][128 + lane]);
        const float gv0 = tanhf_fast(gl[w][256 + lane]);
        const float ov0 = sigf(gl[w][384 + lane]);
        const float iv1 = sigf(gl[w][ 64 + lane]);
        const float fv1 = sigf(gl[w][192 + lane]);
        const float gv1 = tanhf_fast(gl[w][320 + lane]);
        const float ov1 = sigf(gl[w][448 + lane]);
        const float cc0 = fv0*cst0 + iv0*gv0;  cst0 = cc0;
        const float cc1 = fv1*cst1 + iv1*gv1;  cst1 = cc1;
        const float hv0 = ov0*tanhf_fast(cc0); hl0 = hv0;
        const float hv1 = ov1*tanhf_fast(cc1); hl1 = hv1;
        const unsigned short h16a = f2h_bits(hv0);
        const unsigned short h16b = f2h_bits(hv1);

        const unsigned tgt = (unsigned)(t+1);
        unsigned* hb = hq + ((size_t)(tgt & 1u)*B_TOT + (cb + w))*HID;

        // publish IMMEDIATELY: 2 coalesced u32 atomicExch per lane (LLC RMW)
        (void)__hip_atomic_exchange(hb + jw*JSL + lane,
                                    (tgt << 16) | (unsigned)h16a,
                                    __ATOMIC_RELAXED, __HIP_MEMORY_SCOPE_AGENT);
        (void)__hip_atomic_exchange(hb + jw*JSL + 64 + lane,
                                    (tgt << 16) | (unsigned)h16b,
                                    __ATOMIC_RELAXED, __HIP_MEMORY_SCOPE_AGENT);

        // own h + x_{t+1} into act while the publish round-trips
        {
            const int c0 = NIN + jw*JSL + lane;
            const int c1 = c0 + 64;
            *(unsigned short*)(act + w*ROWB + ((c0*2) ^ (w << 4))) = h16a;
            *(unsigned short*)(act + w*ROWB + ((c1*2) ^ (w << 4))) = h16b;
            if (t < T_SEQ-1)
                *(unsigned short*)(act + w*ROWB + ((lane*2) ^ (w << 4))) = f2h_bits(xv);
        }

        // gather the single partner's 128 h: lanes 0..31 poll one dwordx4 each
        {
            u32x4 vv;
            const unsigned* ap = hb + (pjw*JSL + gq*4);
            for (;;) {
                unsigned f = 0u;
                if (pact) {
                    asm volatile(
                        "global_load_dwordx4 %0, %1, off sc0 sc1\n\t"
                        "s_waitcnt vmcnt(0)"
                        : "=v"(vv) : "v"(ap) : "memory");
                    f = ((vv[0]>>16)^tgt)|((vv[1]>>16)^tgt)
                      | ((vv[2]>>16)^tgt)|((vv[3]>>16)^tgt);
                }
                if (!__any(f != 0u)) break;
            }
            if (pact) {
                const int c0 = NIN + pjw*JSL + gq*4;
                const unsigned d0 = (vv[0] & 0xFFFFu) | (vv[1] << 16);
                const unsigned d1 = (vv[2] & 0xFFFFu) | (vv[3] << 16);
                *(unsigned long long*)(act + w*ROWB + ((c0*2) ^ (w << 4))) =
                    ((unsigned long long)d1 << 32) | (unsigned long long)d0;
            }
        }

        __syncthreads();   // B2: act ready for next step
    }

    // ---- final FC: thread holds h(w, jw*128+lane) and +64 ----
    {
        float v = Wfc[jw*JSL + lane]*hl0 + Wfc[jw*JSL + 64 + lane]*hl1;
        if (jw == 0 && lane == 0) v += bfc[0];
        #pragma unroll
        for (int off = 32; off; off >>= 1) v += __shfl_down(v, off);
        if (lane == 0) atomicAdd(&out[cb + w], v);
    }
}

extern "C" void kernel_launch(void* const* d_in, const int* in_sizes, int n_in,
                              void* d_out, int out_size, void* d_ws, size_t ws_size,
                              hipStream_t stream)
{
    const float* x   = (const float*)d_in[0];
    const float* Wih = (const float*)d_in[1];
    const float* Whh = (const float*)d_in[2];
    const float* bih = (const float*)d_in[3];
    const float* bhh = (const float*)d_in[4];
    const float* Wfc = (const float*)d_in[5];
    const float* bfc = (const float*)d_in[6];
    float* out = (float*)d_out;

    unsigned* hq = (unsigned*)d_ws;   // [2][256][256] tagged words

    hipMemsetAsync(hq, 0, (size_t)2*B_TOT*HID*sizeof(unsigned), stream);
    hipMemsetAsync(d_out, 0, out_size*sizeof(float), stream);
    lstm_scan<<<NWG, 1024, 0, stream>>>(x, Wih, Whh, bih, bhh, Wfc, bfc,
                                        out, hq);
}